// Round 6
// baseline (18376.213 us; speedup 1.0000x reference)
//
#include <hip/hip_runtime.h>

#define BB 128
#define TT 512
#define DD 512
#define HH 1024
#define GG 4096  // 4*HH
#define SPIN_MAX 100000

typedef __attribute__((ext_vector_type(8))) short short8;
typedef __attribute__((ext_vector_type(4))) float f32x4;

// f32 -> bf16 bits, round-to-nearest-even
__device__ __forceinline__ unsigned short f2bf(float f) {
  unsigned int u = __float_as_uint(f);
  return (unsigned short)((u + 0x7fffu + ((u >> 16) & 1u)) >> 16);
}

// Persistent LSTM, REGULAR launch (no cooperative API) + manual flag barrier.
// Grid: 256 blocks = 128 col-blocks (8 h-cols x 4 gates = 32 reordered gate cols) x 2 batch-halves.
// Block: 256 threads = 4 waves; wave w owns batch rows [bbk*64 + w*16, +16), all 32 gate cols.
// Reordered gate col lc = g*8 + jj  <->  global col g*1024 + cb*8 + jj   (g: 0=i,1=f,2=g,3=o)
// U slice: 32 cols x 1024 k, bf16, XOR-swizzled, staged once into 64KB LDS from raw f32 U.
// W slice: per-lane B-fragments (32 x short8 = 128 VGPRs), gathered once from raw f32 W.
// x: read f32 per step, packed to bf16 in-register. h: bf16 ping-pong in ws.
// Sync per step: publish flags[bbk*128+cb] = t+1 (release, agent scope) after h writes;
// wait for all 128 same-half flags >= t+1 (acquire, agent scope). 1 block/CU => co-resident.
__launch_bounds__(256, 1)
__global__ void lstm_persistent(const float* __restrict__ x,
                                const float* __restrict__ W,
                                const float* __restrict__ U,
                                const float* __restrict__ b,
                                unsigned short* __restrict__ h0,
                                unsigned short* __restrict__ h1,
                                int* __restrict__ flags,
                                float* __restrict__ out) {
  __shared__ unsigned short Us[32 * 1024];  // 64 KB

  const int bid = blockIdx.x;
  const int cb = bid >> 1;   // 0..127
  const int bbk = bid & 1;   // 0..1
  const int tid = threadIdx.x;
  const int wave = tid >> 6;
  const int lane = tid & 63;
  const int l15 = lane & 15;
  const int lgrp = lane >> 4;  // 0..3

  // ---- one-time: stage U slice into LDS (bf16, swizzled) ----
  // logical (lc, k) stored at byte (lc*2048 + 2k) ^ ((lc&7)<<4)
  for (int idx = tid; idx < 32 * 1024; idx += 256) {
    int k = idx >> 5;
    int lc = idx & 31;
    int g = lc >> 3, jj = lc & 7;
    float uv = U[(size_t)k * GG + g * HH + cb * 8 + jj];
    int byte = lc * 2048 + k * 2;
    int swz = byte ^ ((lc & 7) << 4);
    *(unsigned short*)((char*)Us + swz) = f2bf(uv);
  }

  // ---- one-time: gather W B-fragments into registers ----
  const int jcol = cb * 8 + (l15 & 7);
  const int g0 = l15 >> 3;                  // 0 or 1 (i or f)
  const int gcol0 = g0 * HH + jcol;         // acc0 cols: i|f
  const int gcol1 = (g0 + 2) * HH + jcol;   // acc1 cols: g|o
  short8 wf0[16], wf1[16];
#pragma unroll
  for (int kk = 0; kk < 16; ++kk) {
    int k0 = kk * 32 + lgrp * 8;
#pragma unroll
    for (int j = 0; j < 8; ++j) {
      wf0[kk][j] = (short)f2bf(W[(size_t)(k0 + j) * GG + gcol0]);
      wf1[kk][j] = (short)f2bf(W[(size_t)(k0 + j) * GG + gcol1]);
    }
  }

  const float bv0 = b[gcol0];
  const float bv1 = b[gcol1];

  float cst[4] = {0.f, 0.f, 0.f, 0.f};

  const int rowA = bbk * 64 + wave * 16 + l15;       // A-frag batch row
  const int rowD = bbk * 64 + wave * 16 + lgrp * 4;  // D base row (+r)
  const int hcol = cb * 8 + (l15 & 7);               // owned h col (lanes l15<8)

  const int xr = (l15 & 7) << 4;
  const int base0 = l15 * 2048;

  int* myFlags = flags + bbk * 128;

  __syncthreads();

  for (int t = 0; t < TT; ++t) {
    const unsigned short* hp = (t & 1) ? h1 : h0;
    unsigned short* hn = (t & 1) ? h0 : h1;

    f32x4 a0a = {0.f, 0.f, 0.f, 0.f}, a0b = {0.f, 0.f, 0.f, 0.f};
    f32x4 a1a = {0.f, 0.f, 0.f, 0.f}, a1b = {0.f, 0.f, 0.f, 0.f};

    // ---- input part: z += x_t @ W  (A: f32 x -> bf16 pack; B: registers) ----
    const float* xRow = x + ((size_t)rowA * TT + t) * DD + lgrp * 8;
#pragma unroll
    for (int kk = 0; kk < 16; ++kk) {
      float4 v0 = *(const float4*)(xRow + kk * 32);
      float4 v1 = *(const float4*)(xRow + kk * 32 + 4);
      union { unsigned int u[4]; short8 v; } ax;
      ax.u[0] = (unsigned int)f2bf(v0.x) | ((unsigned int)f2bf(v0.y) << 16);
      ax.u[1] = (unsigned int)f2bf(v0.z) | ((unsigned int)f2bf(v0.w) << 16);
      ax.u[2] = (unsigned int)f2bf(v1.x) | ((unsigned int)f2bf(v1.y) << 16);
      ax.u[3] = (unsigned int)f2bf(v1.z) | ((unsigned int)f2bf(v1.w) << 16);
      if (kk & 1) {
        a0b = __builtin_amdgcn_mfma_f32_16x16x32_bf16(ax.v, wf0[kk], a0b, 0, 0, 0);
        a1b = __builtin_amdgcn_mfma_f32_16x16x32_bf16(ax.v, wf1[kk], a1b, 0, 0, 0);
      } else {
        a0a = __builtin_amdgcn_mfma_f32_16x16x32_bf16(ax.v, wf0[kk], a0a, 0, 0, 0);
        a1a = __builtin_amdgcn_mfma_f32_16x16x32_bf16(ax.v, wf1[kk], a1a, 0, 0, 0);
      }
    }

    // ---- recurrent part: z += h_prev @ U  (A: bf16 h from global; B: LDS) ----
    const unsigned short* aRow = hp + (size_t)rowA * HH + lgrp * 8;
    const char* UsB = (const char*)Us;
#pragma unroll 8
    for (int kk = 0; kk < 32; ++kk) {
      int kbyte = (kk * 64 + lgrp * 16) ^ xr;
      short8 a = *(const short8*)(aRow + kk * 32);
      short8 bu0 = *(const short8*)(UsB + base0 + kbyte);
      short8 bu1 = *(const short8*)(UsB + base0 + 32768 + kbyte);
      if (kk & 1) {
        a0b = __builtin_amdgcn_mfma_f32_16x16x32_bf16(a, bu0, a0b, 0, 0, 0);
        a1b = __builtin_amdgcn_mfma_f32_16x16x32_bf16(a, bu1, a1b, 0, 0, 0);
      } else {
        a0a = __builtin_amdgcn_mfma_f32_16x16x32_bf16(a, bu0, a0a, 0, 0, 0);
        a1a = __builtin_amdgcn_mfma_f32_16x16x32_bf16(a, bu1, a1a, 0, 0, 0);
      }
    }

    // ---- gates ----
    // D layout: col = lane&15, row = rowD + r. acc0 cols: l15<8 = i, >=8 = f.
    // acc1 cols: l15<8 = g, >=8 = o. Pair i/f and g/o via shfl_xor(8).
#pragma unroll
    for (int r = 0; r < 4; ++r) {
      float v0 = a0a[r] + a0b[r] + bv0;
      float v1 = a1a[r] + a1b[r] + bv1;
      float p0 = __shfl_xor(v0, 8, 64);
      float p1 = __shfl_xor(v1, 8, 64);
      if (l15 < 8) {
        float iv = 1.f / (1.f + __expf(-v0));
        float fv = 1.f / (1.f + __expf(-p0));
        float gv = tanhf(v1);
        float ov = 1.f / (1.f + __expf(-p1));
        float cn = fv * cst[r] + iv * gv;
        cst[r] = cn;
        float hv = ov * tanhf(cn);
        int row = rowD + r;
        hn[(size_t)row * HH + hcol] = f2bf(hv);
        out[((size_t)row * TT + t) * HH + hcol] = hv;
      }
    }

    // ---- publish: all block stores drained (syncthreads => vmcnt(0)), then release flag ----
    __syncthreads();
    if (tid == 0) {
      __threadfence();  // agent-scope: L2 writeback so other XCDs see this block's h
      __hip_atomic_store(&myFlags[cb], t + 1, __ATOMIC_RELEASE, __HIP_MEMORY_SCOPE_AGENT);
    }

    // ---- wait: all 128 same-half producers published step t ----
    {
      const int j = tid & 127;
      int spins = 0;
      while (__hip_atomic_load(&myFlags[j], __ATOMIC_ACQUIRE, __HIP_MEMORY_SCOPE_AGENT) < t + 1) {
        if (++spins > SPIN_MAX) break;  // bounded: broken sync => finite garbage, not a hang
        __builtin_amdgcn_s_sleep(8);
      }
    }
    __syncthreads();
  }
}

extern "C" void kernel_launch(void* const* d_in, const int* in_sizes, int n_in,
                              void* d_out, int out_size, void* d_ws, size_t ws_size,
                              hipStream_t stream) {
  const float* x = (const float*)d_in[0];
  const float* W = (const float*)d_in[1];
  const float* U = (const float*)d_in[2];
  const float* b = (const float*)d_in[3];
  float* out = (float*)d_out;

  // ws: h0 (256KB) | h1 (256KB) | flags (1KB). All zero-initialized each call.
  unsigned short* h0 = (unsigned short*)d_ws;
  unsigned short* h1 = (unsigned short*)((char*)d_ws + 262144);
  int* flags = (int*)((char*)d_ws + 524288);

  hipMemsetAsync(d_ws, 0, 524288 + 1024, stream);

  hipLaunchKernelGGL(lstm_persistent, dim3(256), dim3(256), 0, stream,
                     x, W, U, b, h0, h1, flags, out);
}

// Round 7
// 13453.706 us; speedup vs baseline: 1.3659x; 1.3659x over previous
//
#include <hip/hip_runtime.h>

#define BB 128
#define TT 512
#define DD 512
#define HH 1024
#define GG 4096  // 4*HH
#define SPIN_MAX 200000

typedef __attribute__((ext_vector_type(8))) short short8;
typedef __attribute__((ext_vector_type(4))) float f32x4;

// f32 -> bf16 bits, round-to-nearest-even
__device__ __forceinline__ unsigned short f2bf(float f) {
  unsigned int u = __float_as_uint(f);
  return (unsigned short)((u + 0x7fffu + ((u >> 16) & 1u)) >> 16);
}

__device__ __forceinline__ short8 pack8(const float* __restrict__ p) {
  float4 v0 = *(const float4*)p;
  float4 v1 = *(const float4*)(p + 4);
  union { unsigned int u[4]; short8 v; } ax;
  ax.u[0] = (unsigned int)f2bf(v0.x) | ((unsigned int)f2bf(v0.y) << 16);
  ax.u[1] = (unsigned int)f2bf(v0.z) | ((unsigned int)f2bf(v0.w) << 16);
  ax.u[2] = (unsigned int)f2bf(v1.x) | ((unsigned int)f2bf(v1.y) << 16);
  ax.u[3] = (unsigned int)f2bf(v1.z) | ((unsigned int)f2bf(v1.w) << 16);
  return ax.v;
}

// Persistent LSTM, regular launch + counter barrier (1 RMW + 1 poller per block).
// Grid: 256 blocks = 128 col-blocks (32 reordered gate cols) x 2 batch-halves; 1 block/CU.
// Block: 256 threads = 4 waves; wave w owns rows [bbk*64 + w*16, +16), all 32 gate cols.
// Reordered gate col lc = g*8 + jj <-> global col g*1024 + cb*8 + jj (g: 0=i,1=f,2=g,3=o)
// U slice: 32 cols x 1024 k bf16 in 64KB LDS (XOR-swizzled), staged once from f32 U.
// W slice: per-lane B-frags in 128 VGPRs, gathered once. x: prefetched 1 step ahead into
// 64 VGPRs (bf16-packed). h: bf16 ping-pong in ws. Barrier: arrive[(t*2+bbk)*32] counters,
// thread0: fetch_add(RELEASE,AGENT) -> relaxed poll ==128 -> one ACQUIRE load (cache inv).
__launch_bounds__(256, 1)
__global__ void lstm_persistent(const float* __restrict__ x,
                                const float* __restrict__ W,
                                const float* __restrict__ U,
                                const float* __restrict__ b,
                                unsigned short* __restrict__ h0,
                                unsigned short* __restrict__ h1,
                                int* __restrict__ arrive,
                                float* __restrict__ out) {
  __shared__ unsigned short Us[32 * 1024];  // 64 KB

  const int bid = blockIdx.x;
  const int cb = bid >> 1;   // 0..127
  const int bbk = bid & 1;   // 0..1
  const int tid = threadIdx.x;
  const int wave = tid >> 6;
  const int lane = tid & 63;
  const int l15 = lane & 15;
  const int lgrp = lane >> 4;  // 0..3

  // ---- one-time: stage U slice into LDS (bf16, swizzled) ----
  for (int idx = tid; idx < 32 * 1024; idx += 256) {
    int k = idx >> 5;
    int lc = idx & 31;
    int g = lc >> 3, jj = lc & 7;
    float uv = U[(size_t)k * GG + g * HH + cb * 8 + jj];
    int byte = lc * 2048 + k * 2;
    int swz = byte ^ ((lc & 7) << 4);
    *(unsigned short*)((char*)Us + swz) = f2bf(uv);
  }

  // ---- one-time: gather W B-fragments into registers ----
  const int jcol = cb * 8 + (l15 & 7);
  const int g0 = l15 >> 3;
  const int gcol0 = g0 * HH + jcol;         // acc0 cols: i|f
  const int gcol1 = (g0 + 2) * HH + jcol;   // acc1 cols: g|o
  short8 wf0[16], wf1[16];
#pragma unroll
  for (int kk = 0; kk < 16; ++kk) {
    int k0 = kk * 32 + lgrp * 8;
#pragma unroll
    for (int j = 0; j < 8; ++j) {
      wf0[kk][j] = (short)f2bf(W[(size_t)(k0 + j) * GG + gcol0]);
      wf1[kk][j] = (short)f2bf(W[(size_t)(k0 + j) * GG + gcol1]);
    }
  }

  const float bv0 = b[gcol0];
  const float bv1 = b[gcol1];

  float cst[4] = {0.f, 0.f, 0.f, 0.f};

  const int rowA = bbk * 64 + wave * 16 + l15;       // A-frag batch row
  const int rowD = bbk * 64 + wave * 16 + lgrp * 4;  // D base row (+r)
  const int hcol = cb * 8 + (l15 & 7);               // owned h col (lanes l15<8)

  const int xr = (l15 & 7) << 4;
  const int base0 = l15 * 2048;

  __syncthreads();

  // ---- prefetch x fragments for t=0 ----
  short8 xa[16];
  {
    const float* xRow = x + ((size_t)rowA * TT + 0) * DD + lgrp * 8;
#pragma unroll
    for (int kk = 0; kk < 16; ++kk) xa[kk] = pack8(xRow + kk * 32);
  }

  for (int t = 0; t < TT; ++t) {
    const unsigned short* hp = (t & 1) ? h1 : h0;
    unsigned short* hn = (t & 1) ? h0 : h1;

    f32x4 a0a = {0.f, 0.f, 0.f, 0.f}, a0b = {0.f, 0.f, 0.f, 0.f};
    f32x4 a1a = {0.f, 0.f, 0.f, 0.f}, a1b = {0.f, 0.f, 0.f, 0.f};

    const unsigned short* aRow = hp + (size_t)rowA * HH + lgrp * 8;
    const char* UsB = (const char*)Us;

    // ---- issue h chunk A (kk=0..15): 16 loads in flight ----
    short8 hA[16];
#pragma unroll
    for (int kk = 0; kk < 16; ++kk) hA[kk] = *(const short8*)(aRow + kk * 32);

    // ---- x-part MFMAs on prefetched regs (covers h-load latency) ----
#pragma unroll
    for (int kk = 0; kk < 16; ++kk) {
      if (kk & 1) {
        a0b = __builtin_amdgcn_mfma_f32_16x16x32_bf16(xa[kk], wf0[kk], a0b, 0, 0, 0);
        a1b = __builtin_amdgcn_mfma_f32_16x16x32_bf16(xa[kk], wf1[kk], a1b, 0, 0, 0);
      } else {
        a0a = __builtin_amdgcn_mfma_f32_16x16x32_bf16(xa[kk], wf0[kk], a0a, 0, 0, 0);
        a1a = __builtin_amdgcn_mfma_f32_16x16x32_bf16(xa[kk], wf1[kk], a1a, 0, 0, 0);
      }
    }

    // ---- consume chunk A ----
#pragma unroll
    for (int kk = 0; kk < 16; ++kk) {
      int kbyte = (kk * 64 + lgrp * 16) ^ xr;
      short8 bu0 = *(const short8*)(UsB + base0 + kbyte);
      short8 bu1 = *(const short8*)(UsB + base0 + 32768 + kbyte);
      if (kk & 1) {
        a0b = __builtin_amdgcn_mfma_f32_16x16x32_bf16(hA[kk], bu0, a0b, 0, 0, 0);
        a1b = __builtin_amdgcn_mfma_f32_16x16x32_bf16(hA[kk], bu1, a1b, 0, 0, 0);
      } else {
        a0a = __builtin_amdgcn_mfma_f32_16x16x32_bf16(hA[kk], bu0, a0a, 0, 0, 0);
        a1a = __builtin_amdgcn_mfma_f32_16x16x32_bf16(hA[kk], bu1, a1a, 0, 0, 0);
      }
    }

    // ---- issue + consume chunk B (kk=16..31) ----
    short8 hB[16];
#pragma unroll
    for (int kk = 0; kk < 16; ++kk) hB[kk] = *(const short8*)(aRow + (16 + kk) * 32);
#pragma unroll
    for (int kk = 0; kk < 16; ++kk) {
      int kbyte = ((16 + kk) * 64 + lgrp * 16) ^ xr;
      short8 bu0 = *(const short8*)(UsB + base0 + kbyte);
      short8 bu1 = *(const short8*)(UsB + base0 + 32768 + kbyte);
      if (kk & 1) {
        a0b = __builtin_amdgcn_mfma_f32_16x16x32_bf16(hB[kk], bu0, a0b, 0, 0, 0);
        a1b = __builtin_amdgcn_mfma_f32_16x16x32_bf16(hB[kk], bu1, a1b, 0, 0, 0);
      } else {
        a0a = __builtin_amdgcn_mfma_f32_16x16x32_bf16(hB[kk], bu0, a0a, 0, 0, 0);
        a1a = __builtin_amdgcn_mfma_f32_16x16x32_bf16(hB[kk], bu1, a1a, 0, 0, 0);
      }
    }

    // ---- prefetch x for t+1 (independent of barrier; overlaps gates) ----
    if (t + 1 < TT) {
      const float* xRowN = x + ((size_t)rowA * TT + (t + 1)) * DD + lgrp * 8;
#pragma unroll
      for (int kk = 0; kk < 16; ++kk) xa[kk] = pack8(xRowN + kk * 32);
    }

    // ---- gates ----
#pragma unroll
    for (int r = 0; r < 4; ++r) {
      float v0 = a0a[r] + a0b[r] + bv0;
      float v1 = a1a[r] + a1b[r] + bv1;
      float p0 = __shfl_xor(v0, 8, 64);
      float p1 = __shfl_xor(v1, 8, 64);
      if (l15 < 8) {
        float iv = 1.f / (1.f + __expf(-v0));
        float fv = 1.f / (1.f + __expf(-p0));
        float gv = tanhf(v1);
        float ov = 1.f / (1.f + __expf(-p1));
        float cn = fv * cst[r] + iv * gv;
        cst[r] = cn;
        float hv = ov * tanhf(cn);
        int row = rowD + r;
        hn[(size_t)row * HH + hcol] = f2bf(hv);
        out[((size_t)row * TT + t) * HH + hcol] = hv;
      }
    }

    // ---- barrier: per-half arrival counter, single poller ----
    __syncthreads();  // all waves' stores drained to L2 (vmcnt(0) before s_barrier)
    if (tid == 0) {
      int* slot = arrive + ((size_t)t * 2 + bbk) * 32;  // 128B-padded slot
      __hip_atomic_fetch_add(slot, 1, __ATOMIC_RELEASE, __HIP_MEMORY_SCOPE_AGENT);
      int spins = 0;
      while (__hip_atomic_load(slot, __ATOMIC_RELAXED, __HIP_MEMORY_SCOPE_AGENT) < 128) {
        if (++spins > SPIN_MAX) break;  // bounded: broken sync => garbage, not hang
        __builtin_amdgcn_s_sleep(2);
      }
      // acquire: orders + invalidates L1 (CU-wide) / L2 (XCD-wide) for the whole block
      (void)__hip_atomic_load(slot, __ATOMIC_ACQUIRE, __HIP_MEMORY_SCOPE_AGENT);
    }
    __syncthreads();
  }
}

extern "C" void kernel_launch(void* const* d_in, const int* in_sizes, int n_in,
                              void* d_out, int out_size, void* d_ws, size_t ws_size,
                              hipStream_t stream) {
  const float* x = (const float*)d_in[0];
  const float* W = (const float*)d_in[1];
  const float* U = (const float*)d_in[2];
  const float* b = (const float*)d_in[3];
  float* out = (float*)d_out;

  // ws: h0 (256KB) | h1 (256KB) | arrive (512 steps * 2 halves * 32 ints = 128KB)
  unsigned short* h0 = (unsigned short*)d_ws;
  unsigned short* h1 = (unsigned short*)((char*)d_ws + 262144);
  int* arrive = (int*)((char*)d_ws + 524288);

  hipMemsetAsync(d_ws, 0, 524288 + 131072, stream);

  hipLaunchKernelGGL(lstm_persistent, dim3(256), dim3(256), 0, stream,
                     x, W, U, b, h0, h1, arrive, out);
}